// Round 15
// baseline (186.720 us; speedup 1.0000x reference)
//
#include <hip/hip_runtime.h>
#include <hip/hip_fp16.h>

#define HID 64
#define ELLK 32   // slots/node; kept degree ~Poisson(5.5), max over 100k ~18
#define CUT_D2 132.5471f   // drop rbf < 1e-5 (R10: measured no absmax change)

typedef _Float16 half8 __attribute__((ext_vector_type(8)));
typedef float f32x4 __attribute__((ext_vector_type(4)));

__device__ __forceinline__ float rbf_of(unsigned w) {
    return __half2float(__ushort_as_half((unsigned short)(w & 0x7fff)));
}

// x16[n][h] = fp16(emb[z[n]][h]); zeroes ELL counters; packs pos4 (R31).
__global__ void embed_kernel(const int* __restrict__ z, const float* __restrict__ emb,
                             const float* __restrict__ pos, float4* __restrict__ pos4,
                             __half* __restrict__ x16, int* __restrict__ cnt, int n) {
    int t = blockIdx.x * blockDim.x + threadIdx.x;
    if (t <= n) cnt[t] = 0;
    if (t < n) {                       // pos -> pos4 (single-line 16B records)
        float4 p;
        p.x = pos[3 * t];
        p.y = pos[3 * t + 1];
        p.z = pos[3 * t + 2];
        p.w = 0.f;
        pos4[t] = p;
    }
    if (t >= n * HID / 2) return;
    int node = t >> 5, h2 = (t & 31) * 2;
    const float* src = emb + z[node] * HID + h2;
    __half2 v;
    v.x = __float2half(src[0]);
    v.y = __float2half(src[1]);
    *(__half2*)(x16 + (size_t)node * HID + h2) = v;
}

// ELL fill + fused rbf for KEPT edges; packed record (col<<15)|fp16(rbf).
__global__ void fill_kernel(const int* __restrict__ row, const int* __restrict__ col,
                            const float4* __restrict__ pos4, int* __restrict__ cnt,
                            unsigned* __restrict__ ell, int e) {
    int t = blockIdx.x * blockDim.x + threadIdx.x;
    if (t >= e) return;
    int r = row[t], c = col[t];
    float4 pr = pos4[r];
    float4 pc = pos4[c];
    float dx = pr.x - pc.x;
    float dy = pr.y - pc.y;
    float dz = pr.z - pc.z;
    float d2 = dx * dx + dy * dy + dz * dz;
    if (d2 > CUT_D2) return;
    float rbf = expf(-sqrtf(d2));
    unsigned short hb = __half_as_ushort(__float2half(rbf));
    int p = atomicAdd(&cnt[r], 1);
    if (p < ELLK) ell[(size_t)r * ELLK + p] = ((unsigned)c << 15) | (unsigned)hb;
}

// R32: fused layer, BARRIER-FREE PER-WAVE PIPELINE (duplicated-row MFMA).
// R27's second __syncthreads convoys all 8 waves on the block's slowest pack
// (max of 8 Poisson degrees ~1.4x mean) and serializes the MFMA stage. R28's
// barrier removal failed only because it bundled a 16-node/2-stream wave
// (register overflow -> spills). R32 keeps the R27 one-pack gather VERBATIM
// and removes the coupling instead: each wave MFMAs ITS OWN 8 rows with the
// A-fragment row index duplicated (r16&7). The 16x64 MFMA computes rows 0-7
// twice; quad 0-1 lanes store the valid copy, quad 2-3 discard duplicates.
// MFMA is per-row (D[j]=A[j]B) -> valid rows bit-identical (absmax 0.00390625).
// Cost: 2x MFMA ops (MfmaUtil 0.5->1%, irrelevant) + 4 extra wlds reads/wave.
// Gain: only barrier left is W-preload (BEFORE gather, no convoy); wave flows
// gather -> LDS write -> lgkmcnt -> MFMA -> store, fully decoupled.
// Registers: gather (~55) and MFMA (~30) states are sequential -> reuse, no
// new peak (spill check = WRITE_SIZE).
__global__ void __launch_bounds__(512)
layer_kernel(const __half* __restrict__ x16, const int* __restrict__ cnt,
             const unsigned* __restrict__ ell,
             const float* __restrict__ W, const float* __restrict__ b,
             float* __restrict__ out32, __half* __restrict__ out16, int n) {
    __shared__ __align__(16) __half ltile[8][8 * HID];    // 1KB per wave (8 rows)
    __shared__ __align__(16) __half wlds[8][64][8];       // 8KB: [frag][lane][8 halves]
    int tid = threadIdx.x;
    int lane = tid & 63;
    int wv = tid >> 6;                 // wave 0..7

    int grp = lane >> 3;               // gather: group = node within the pack
    int gl  = lane & 7;                // gather: lane within group = h-chunk
    int r16 = lane & 15;               // mfma: A row / out col
    int quad = lane >> 4;              // mfma: k-chunk / out row group

    // ---- W -> LDS preload (512 threads, 512 frag-slots, 1 each) ----
    {
        int f = tid >> 6, l = tid & 63;
        int ht = f >> 1, kt = f & 1, q = l >> 4, r = l & 15;
        const float* src = W + (ht * 16 + r) * HID + kt * 32 + q * 8;
        half8 h;
#pragma unroll
        for (int j = 0; j < 8; ++j) h[j] = (_Float16)src[j];
        *(half8*)&wlds[f][l][0] = h;
    }
    float biasv[4];
#pragma unroll
    for (int ht = 0; ht < 4; ++ht) biasv[ht] = b[ht * 16 + r16];
    __syncthreads();                   // the ONLY barrier: wlds ready (pre-gather)

    int npack = (n + 7) >> 3;
    int p = (blockIdx.x << 3) + wv;    // one 8-node pack per wave
    if (p >= npack) return;            // no barriers below -> safe
    int pbase = p << 3;
    char* tile = (char*)&ltile[wv][0];

    // ================= gather: one 8-node pack (R27 body verbatim) ============
    {
        int own = pbase + grp; if (own >= n) own = n - 1;  // clamp (loads only)

        int cn = pbase + (lane & 7);
        int myc = cnt[cn < n ? cn : n - 1];
        if (cn >= n) myc = 0;
        if (myc > ELLK) myc = ELLK;

        unsigned rec[4];
#pragma unroll
        for (int r = 0; r < 4; ++r)
            rec[r] = ell[(size_t)own * ELLK + r * 8 + gl];

        half8 res = *(const half8*)(x16 + (size_t)own * HID + gl * 8);

        int c_own = __shfl(myc, grp);                      // uniform within group
#pragma unroll
        for (int r = 0; r < 4; ++r)
            if (r * 8 + gl >= c_own) rec[r] = (unsigned)own << 15;  // rbf=0 no-op

        float acc[8];
#pragma unroll
        for (int k = 0; k < 8; ++k) acc[k] = (float)res[k];

#pragma unroll
        for (int r = 0; r < 4; ++r) {
            if (8 * r < c_own) {                       // group-uniform octet guard
#pragma unroll
                for (int i = 0; i < 8; ++i) {
                    unsigned w = __shfl(rec[r], (lane & 56) + i);
                    half8 v = *(const half8*)(x16 + (size_t)(w >> 15) * HID + gl * 8);
                    float f = rbf_of(w);               // pre-masked: 0 if dead
#pragma unroll
                    for (int k = 0; k < 8; ++k)
                        acc[k] = fmaf((float)v[k], f, acc[k]);
                }
            }
        }

        half8 o;
#pragma unroll
        for (int k = 0; k < 8; ++k) o[k] = (_Float16)acc[k];
        int ni = grp;                                  // row 0..7 in own region
        *(half8*)(tile + ni * 128 + ((gl << 4) ^ (ni << 4))) = o;
    }

    // ======= mfma: SAME wave, own 8 rows duplicated in A (lgkmcnt-only RAW) ===
    {
        const half8* wl = (const half8*)&wlds[0][0][0];
        int rr = r16 & 7;                              // duplicated row index
        half8 afrag0 = *(const half8*)(tile + rr * 128 + ((quad << 4) ^ (rr << 4)));
        half8 afrag1 = *(const half8*)(tile + rr * 128 + (((quad + 4) << 4) ^ (rr << 4)));
#pragma unroll
        for (int ht = 0; ht < 4; ++ht) {
            f32x4 acc = {biasv[ht], biasv[ht], biasv[ht], biasv[ht]};
            half8 b0 = wl[(ht * 2 + 0) * 64 + lane];   // stride-1 ds_read_b128
            half8 b1 = wl[(ht * 2 + 1) * 64 + lane];
            acc = __builtin_amdgcn_mfma_f32_16x16x32_f16(afrag0, b0, acc, 0, 0, 0);
            acc = __builtin_amdgcn_mfma_f32_16x16x32_f16(afrag1, b1, acc, 0, 0, 0);
            if (quad < 2) {                            // quad 2-3 hold duplicates
#pragma unroll
                for (int r = 0; r < 4; ++r) {
                    int row = pbase + quad * 4 + r;    // rows 0..7 of the pack
                    if (row < n) {
                        float v = fmaxf(acc[r], 0.0f);
                        size_t idx = (size_t)row * HID + ht * 16 + r16;
                        if (out32) out32[idx] = v;
                        if (out16) out16[idx] = __float2half(v);
                    }
                }
            }
        }
    }
}

extern "C" void kernel_launch(void* const* d_in, const int* in_sizes, int n_in,
                              void* d_out, int out_size, void* d_ws, size_t ws_size,
                              hipStream_t stream) {
    const int*   z    = (const int*)d_in[0];
    const float* pos  = (const float*)d_in[1];
    const int*   eidx = (const int*)d_in[2];
    const float* emb  = (const float*)d_in[3];
    const float* Ws   = (const float*)d_in[4];
    const float* bs   = (const float*)d_in[5];
    int n = in_sizes[0];
    int e = in_sizes[2] / 2;
    int nlayers = in_sizes[4] / (HID * HID);
    const int* row = eidx;
    const int* col = eidx + e;
    float* out = (float*)d_out;

    char* ws = (char*)d_ws;
    __half*   X16 = (__half*)ws;                                   // n*64 fp16 (12.8 MB)
    __half*   Y16 = X16 + (size_t)n * HID;                         // n*64 fp16 (ping-pong)
    unsigned* ell = (unsigned*)((char*)Y16 + (size_t)n * HID * 2); // (n+2)*ELLK u32
    int*      cnt = (int*)((char*)ell + (size_t)(n + 2) * ELLK * 4); // n+1 ints
    float4*   pos4 = (float4*)((char*)cnt + (((size_t)(n + 1) * 4 + 15) & ~(size_t)15));

    // 5 dispatches: embed(+cnt zero+pos4), fill, 3x fused layer (barrier-free)
    embed_kernel<<<(n * HID / 2 + 255) / 256, 256, 0, stream>>>(z, emb, pos, pos4, X16, cnt, n);
    fill_kernel<<<(e + 255) / 256, 256, 0, stream>>>(row, col, pos4, cnt, ell, e);

    int npack = (n + 7) >> 3;
    int lblocks = (npack + 7) >> 3;    // 8 waves/block, 1 pack/wave
    for (int l = 0; l < nlayers; ++l) {
        bool last = (l == nlayers - 1);
        const __half* src = (l & 1) ? Y16 : X16;   // ping-pong: fused kernel reads
        __half*       dst = (l & 1) ? X16 : Y16;   // src everywhere while writing dst
        layer_kernel<<<lblocks, 512, 0, stream>>>(src, cnt, ell,
                                                  Ws + (size_t)l * HID * HID,
                                                  bs + (size_t)l * HID,
                                                  last ? out : nullptr,
                                                  last ? nullptr : dst, n);
    }
}

// Round 16
// 176.050 us; speedup vs baseline: 1.0606x; 1.0606x over previous
//
#include <hip/hip_runtime.h>
#include <hip/hip_fp16.h>

#define HID 64
#define ELLK 32   // slots/node; kept degree ~Poisson(5.5), max over 100k ~18
#define CUT_D2 132.5471f   // drop rbf < 1e-5 (R10: measured no absmax change)

typedef _Float16 half8 __attribute__((ext_vector_type(8)));
typedef float f32x4 __attribute__((ext_vector_type(4)));

__device__ __forceinline__ float rbf_of(unsigned w) {
    return __half2float(__ushort_as_half((unsigned short)(w & 0x7fff)));
}

// x16[n][h] = fp16(emb[z[n]][h]); zeroes ELL counters; packs pos4 (R31).
__global__ void embed_kernel(const int* __restrict__ z, const float* __restrict__ emb,
                             const float* __restrict__ pos, float4* __restrict__ pos4,
                             __half* __restrict__ x16, int* __restrict__ cnt, int n) {
    int t = blockIdx.x * blockDim.x + threadIdx.x;
    if (t <= n) cnt[t] = 0;
    if (t < n) {                       // pos -> pos4 (single-line 16B records)
        float4 p;
        p.x = pos[3 * t];
        p.y = pos[3 * t + 1];
        p.z = pos[3 * t + 2];
        p.w = 0.f;
        pos4[t] = p;
    }
    if (t >= n * HID / 2) return;
    int node = t >> 5, h2 = (t & 31) * 2;
    const float* src = emb + z[node] * HID + h2;
    __half2 v;
    v.x = __float2half(src[0]);
    v.y = __float2half(src[1]);
    *(__half2*)(x16 + (size_t)node * HID + h2) = v;
}

// ELL fill + fused rbf for KEPT edges; packed record (col<<15)|fp16(rbf).
__global__ void fill_kernel(const int* __restrict__ row, const int* __restrict__ col,
                            const float4* __restrict__ pos4, int* __restrict__ cnt,
                            unsigned* __restrict__ ell, int e) {
    int t = blockIdx.x * blockDim.x + threadIdx.x;
    if (t >= e) return;
    int r = row[t], c = col[t];
    float4 pr = pos4[r];
    float4 pc = pos4[c];
    float dx = pr.x - pc.x;
    float dy = pr.y - pc.y;
    float dz = pr.z - pc.z;
    float d2 = dx * dx + dy * dy + dz * dz;
    if (d2 > CUT_D2) return;
    float rbf = expf(-sqrtf(d2));
    unsigned short hb = __half_as_ushort(__float2half(rbf));
    int p = atomicAdd(&cnt[r], 1);
    if (p < ELLK) ell[(size_t)r * ELLK + p] = ((unsigned)c << 15) | (unsigned)hb;
}

// R33: R27 champion body at HALF BLOCK SIZE (256 thr = 4 waves, 2 tiles).
// R32 post-mortem: killing the barrier via duplicated-row MFMA cost more than
// the convoy it saved (2x MFMA, 2x wlds reads, half-width stores: -10us).
// R33 keeps the R25/R27 wave-specialized math VERBATIM and shrinks the convoy
// instead: the post-gather barrier waits on max of 4 pack-degrees, not 8
// (E[max] 1.74 -> 1.55 octets, ~11% less convoyed work), plus finer dispatch
// granularity (3125 blocks) for load-balance under degree variance.
// Mapping: wave w gathers pack w -> tile (w>>1) rows (w&1)*8..; MFMA: wave w
// -> tile (w&1), ht-half (w>>1). Same per-wave ops as R25 -> bit-identical
// (absmax 0.00390625). LDS 12KB; 256 thr -> 8 blocks/CU (wave-capped).
__global__ void __launch_bounds__(256)
layer_kernel(const __half* __restrict__ x16, const int* __restrict__ cnt,
             const unsigned* __restrict__ ell,
             const float* __restrict__ W, const float* __restrict__ b,
             float* __restrict__ out32, __half* __restrict__ out16, int n) {
    __shared__ __align__(16) __half ltile[2][16 * HID];   // 4KB: 2 tiles
    __shared__ __align__(16) __half wlds[8][64][8];       // 8KB: [frag][lane][8 halves]
    int tid = threadIdx.x;
    int lane = tid & 63;
    int wv = tid >> 6;                 // wave 0..3

    int grp = lane >> 3;               // gather: group = node within the pack
    int gl  = lane & 7;                // gather: lane within group = h-chunk
    int r16 = lane & 15;               // mfma: A row / out col
    int quad = lane >> 4;              // mfma: k-chunk / out row group

    // ---- W -> LDS preload (256 threads, 512 frag-slots, 2 each — R22 loop) ----
#pragma unroll
    for (int s0 = 0; s0 < 2; ++s0) {
        int s = tid + s0 * 256;                    // s = f*64 + l
        int f = s >> 6, l = s & 63;
        int ht = f >> 1, kt = f & 1, q = l >> 4, r = l & 15;
        const float* src = W + (ht * 16 + r) * HID + kt * 32 + q * 8;
        half8 h;
#pragma unroll
        for (int j = 0; j < 8; ++j) h[j] = (_Float16)src[j];
        *(half8*)&wlds[f][l][0] = h;
    }
    float biasv[4];
#pragma unroll
    for (int ht = 0; ht < 4; ++ht) biasv[ht] = b[ht * 16 + r16];
    __syncthreads();

    int ntiles = (n + 15) >> 4;
    int Tb = blockIdx.x << 1;          // first tile of this block (2 tiles)

    // ================= gather phase: one 8-node pack per wave =================
    {
        int n8 = (Tb << 4) + (wv << 3);                    // pack base node
        int own = n8 + grp; if (own >= n) own = n - 1;     // clamp (loads only)

        int cn = n8 + (lane & 7);
        int myc = cnt[cn < n ? cn : n - 1];
        if (cn >= n) myc = 0;
        if (myc > ELLK) myc = ELLK;

        unsigned rec[4];
#pragma unroll
        for (int r = 0; r < 4; ++r)
            rec[r] = ell[(size_t)own * ELLK + r * 8 + gl];

        half8 res = *(const half8*)(x16 + (size_t)own * HID + gl * 8);

        int c_own = __shfl(myc, grp);                      // uniform within group
#pragma unroll
        for (int r = 0; r < 4; ++r)
            if (r * 8 + gl >= c_own) rec[r] = (unsigned)own << 15;  // rbf=0 no-op

        float acc[8];
#pragma unroll
        for (int k = 0; k < 8; ++k) acc[k] = (float)res[k];

#pragma unroll
        for (int r = 0; r < 4; ++r) {
            if (8 * r < c_own) {                       // group-uniform octet guard
#pragma unroll
                for (int i = 0; i < 8; ++i) {
                    unsigned w = __shfl(rec[r], (lane & 56) + i);
                    half8 v = *(const half8*)(x16 + (size_t)(w >> 15) * HID + gl * 8);
                    float f = rbf_of(w);               // pre-masked: 0 if dead
#pragma unroll
                    for (int k = 0; k < 8; ++k)
                        acc[k] = fmaf((float)v[k], f, acc[k]);
                }
            }
        }

        half8 o;
#pragma unroll
        for (int k = 0; k < 8; ++k) o[k] = (_Float16)acc[k];
        // wave wv -> tile wv/2, rows (wv&1)*8+grp; swizzled (R23 layout)
        char* tile = (char*)&ltile[wv >> 1][0];
        int ni = ((wv & 1) << 3) + grp;
        *(half8*)(tile + ni * 128 + ((gl << 4) ^ ((ni & 7) << 4))) = o;
    }
    __syncthreads();                   // convoy over 4 packs (was 8)

    // ================= mfma phase: wave w -> tile (w&1), ht-half (w>>1) =======
    {
        int tw = wv & 1;
        int t = Tb + tw;
        if (t < ntiles) {
            int tbase = t << 4;
            char* tile = (char*)&ltile[tw][0];
            const half8* wl = (const half8*)&wlds[0][0][0];
            half8 afrag0 = *(const half8*)(tile + r16 * 128 + ((quad << 4) ^ ((r16 & 7) << 4)));
            half8 afrag1 = *(const half8*)(tile + r16 * 128 + (((quad + 4) << 4) ^ ((r16 & 7) << 4)));
            int htb = (wv >> 1) << 1;                  // 0 or 2
#pragma unroll
            for (int hh = 0; hh < 2; ++hh) {
                int ht = htb + hh;
                f32x4 acc = {biasv[ht], biasv[ht], biasv[ht], biasv[ht]};
                half8 b0 = wl[(ht * 2 + 0) * 64 + lane];   // stride-1 ds_read_b128
                half8 b1 = wl[(ht * 2 + 1) * 64 + lane];
                acc = __builtin_amdgcn_mfma_f32_16x16x32_f16(afrag0, b0, acc, 0, 0, 0);
                acc = __builtin_amdgcn_mfma_f32_16x16x32_f16(afrag1, b1, acc, 0, 0, 0);
#pragma unroll
                for (int r = 0; r < 4; ++r) {
                    int row = tbase + quad * 4 + r;
                    if (row < n) {                     // guards garbage tail rows too
                        float v = fmaxf(acc[r], 0.0f);
                        size_t idx = (size_t)row * HID + ht * 16 + r16;
                        if (out32) out32[idx] = v;
                        if (out16) out16[idx] = __float2half(v);
                    }
                }
            }
        }
    }
}

extern "C" void kernel_launch(void* const* d_in, const int* in_sizes, int n_in,
                              void* d_out, int out_size, void* d_ws, size_t ws_size,
                              hipStream_t stream) {
    const int*   z    = (const int*)d_in[0];
    const float* pos  = (const float*)d_in[1];
    const int*   eidx = (const int*)d_in[2];
    const float* emb  = (const float*)d_in[3];
    const float* Ws   = (const float*)d_in[4];
    const float* bs   = (const float*)d_in[5];
    int n = in_sizes[0];
    int e = in_sizes[2] / 2;
    int nlayers = in_sizes[4] / (HID * HID);
    const int* row = eidx;
    const int* col = eidx + e;
    float* out = (float*)d_out;

    char* ws = (char*)d_ws;
    __half*   X16 = (__half*)ws;                                   // n*64 fp16 (12.8 MB)
    __half*   Y16 = X16 + (size_t)n * HID;                         // n*64 fp16 (ping-pong)
    unsigned* ell = (unsigned*)((char*)Y16 + (size_t)n * HID * 2); // (n+2)*ELLK u32
    int*      cnt = (int*)((char*)ell + (size_t)(n + 2) * ELLK * 4); // n+1 ints
    float4*   pos4 = (float4*)((char*)cnt + (((size_t)(n + 1) * 4 + 15) & ~(size_t)15));

    // 5 dispatches: embed(+cnt zero+pos4), fill, 3x fused layer (2-tile blocks)
    embed_kernel<<<(n * HID / 2 + 255) / 256, 256, 0, stream>>>(z, emb, pos, pos4, X16, cnt, n);
    fill_kernel<<<(e + 255) / 256, 256, 0, stream>>>(row, col, pos4, cnt, ell, e);

    int ntiles = (n + 15) >> 4;
    int lblocks = (ntiles + 1) >> 1;   // 2 tiles/block (4 waves: 4 packs)
    for (int l = 0; l < nlayers; ++l) {
        bool last = (l == nlayers - 1);
        const __half* src = (l & 1) ? Y16 : X16;   // ping-pong: fused kernel reads
        __half*       dst = (l & 1) ? X16 : Y16;   // src everywhere while writing dst
        layer_kernel<<<lblocks, 256, 0, stream>>>(src, cnt, ell,
                                                  Ws + (size_t)l * HID * HID,
                                                  bs + (size_t)l * HID,
                                                  last ? out : nullptr,
                                                  last ? nullptr : dst, n);
    }
}